// Round 3
// baseline (236.516 us; speedup 1.0000x reference)
//
#include <hip/hip_runtime.h>
#include <cstdint>

// Problem constants
#define BB 256
#define TT 128
#define DD 300
#define HH 16
#define GG 64     // 4*H
#define CC 5
#define KC 60     // K-chunk size
#define NCH 5     // 300 / 60

// ---------------------------------------------------------------------------
// Fully fused: one block per batch element (256 blocks x 256 threads).
// Phase 1: xg[128 rows][64 gates] GEMM into LDS, K chunked by 60,
//          register-pipelined staging (load chunk k+1 while computing k).
//          Thread tile: 8 rows (row = ty + 16*r) x 4 cols (tx*4..+3).
// Phase 2: wave 0 runs the 128-step LSTM recurrence from LDS.
// Phase 3: all threads do the [128x16]@[16x5] output projection.
// ---------------------------------------------------------------------------
__global__ __launch_bounds__(256) void lstm_fused_kernel(
    const int* __restrict__ x, const float* __restrict__ emb,
    const float* __restrict__ W_ih, const float* __restrict__ W_hh,
    const float* __restrict__ b_ih, const float* __restrict__ b_hh,
    const float* __restrict__ W_out, const float* __restrict__ b_out,
    float* __restrict__ out) {

  __shared__ float As[TT * KC];    // 30.7 KB [row][d], stride 60 (240B, 16B-aligned)
  __shared__ float Ws[KC * 68];    // 16.3 KB [d][col] transposed, stride 68
  __shared__ float xgs[TT * GG];   // 32 KB gate preactivations
  __shared__ float hsm[TT * HH];   // 8 KB hidden states
  __shared__ int   xid[TT];

  const int t  = threadIdx.x;
  const int b  = blockIdx.x;
  const int tx = t & 15;
  const int ty = t >> 4;

  if (t < TT) xid[t] = x[b * TT + t];
  __syncthreads();

  // Per-thread staging quotas (wave-uniform: boundaries at t=128 and t=192)
  const int na = (t < 128) ? 8 : 7;   // A: 128 rows x 15 float4 = 1920
  const int nw = (t < 192) ? 4 : 3;   // W: 64 cols x 15 float4 = 960

  float4 apf[8];
  float4 wpf[4];

  auto load_chunk = [&](int dbase) {
#pragma unroll
    for (int i = 0; i < 8; i++) {
      if (i < na) {
        int u = t + 256 * i;
        int r = u / 15, f = u - r * 15;
        apf[i] = *(const float4*)(emb + (size_t)xid[r] * DD + dbase + 4 * f);
      }
    }
#pragma unroll
    for (int i = 0; i < 4; i++) {
      if (i < nw) {
        int u = t + 256 * i;
        int c = u / 15, f = u - c * 15;
        wpf[i] = *(const float4*)(W_ih + c * DD + dbase + 4 * f);
      }
    }
  };

  auto store_chunk = [&]() {
#pragma unroll
    for (int i = 0; i < 8; i++) {
      if (i < na) {
        int u = t + 256 * i;
        int r = u / 15, f = u - r * 15;
        *(float4*)&As[r * KC + 4 * f] = apf[i];
      }
    }
#pragma unroll
    for (int i = 0; i < 4; i++) {
      if (i < nw) {
        int u = t + 256 * i;
        int c = u / 15, f = u - c * 15;
        Ws[(4 * f + 0) * 68 + c] = wpf[i].x;
        Ws[(4 * f + 1) * 68 + c] = wpf[i].y;
        Ws[(4 * f + 2) * 68 + c] = wpf[i].z;
        Ws[(4 * f + 3) * 68 + c] = wpf[i].w;
      }
    }
  };

  float acc[8][4] = {};

  load_chunk(0);
  for (int ch = 0; ch < NCH; ch++) {
    if (ch > 0) __syncthreads();   // previous chunk's compute done; LDS free
    store_chunk();
    __syncthreads();               // staged data visible
    if (ch + 1 < NCH) load_chunk((ch + 1) * KC);  // prefetch next into regs

#pragma unroll
    for (int q = 0; q < 15; q++) {
      float4 wc[4];
#pragma unroll
      for (int j = 0; j < 4; j++)
        wc[j] = *(const float4*)&Ws[(q * 4 + j) * 68 + tx * 4];
      // wc[j][c] = W_ih[col 4tx+c][k = 4q+j]
#pragma unroll
      for (int r = 0; r < 8; r++) {
        const int row = ty + 16 * r;
        float4 a = *(const float4*)&As[row * KC + q * 4];
#pragma unroll
        for (int c = 0; c < 4; c++) {
          acc[r][c] = fmaf(a.x, ((const float*)&wc[0])[c], acc[r][c]);
          acc[r][c] = fmaf(a.y, ((const float*)&wc[1])[c], acc[r][c]);
          acc[r][c] = fmaf(a.z, ((const float*)&wc[2])[c], acc[r][c]);
          acc[r][c] = fmaf(a.w, ((const float*)&wc[3])[c], acc[r][c]);
        }
      }
    }
  }

  // Bias + write xg tile to LDS
  float bias[4];
#pragma unroll
  for (int c = 0; c < 4; c++)
    bias[c] = b_ih[tx * 4 + c] + b_hh[tx * 4 + c];
#pragma unroll
  for (int r = 0; r < 8; r++) {
    const int row = ty + 16 * r;
    float4 o;
    o.x = acc[r][0] + bias[0];
    o.y = acc[r][1] + bias[1];
    o.z = acc[r][2] + bias[2];
    o.w = acc[r][3] + bias[3];
    *(float4*)&xgs[row * GG + tx * 4] = o;
  }
  __syncthreads();

  // ---- Phase 2: LSTM recurrence (wave 0 only) ----
  if (t < 64) {
    const int lane = t;
    const int k = lane & 15;
    const int gate = lane >> 4;
    const bool is_tanh = (gate == 2);
    const float L2E = 1.4426950408889634f;
    const float gscale = is_tanh ? (-2.0f * L2E) : (-L2E);  // exp2-domain

    float wh[16];
    {
      const float* wr = W_hh + lane * HH;
#pragma unroll
      for (int kk = 0; kk < 16; kk++) wh[kk] = wr[kk];
    }

    float c = 0.0f;
    float hu[16];
#pragma unroll
    for (int kk = 0; kk < 16; kk++) hu[kk] = 0.0f;

    float g = xgs[lane];
    for (int tstep = 0; tstep < TT; tstep++) {
      float gnext = xgs[((tstep + 1) & 127) * GG + lane];

      // g += h . W_hh[j,:]  (4 split accumulators)
      float a0 = fmaf(hu[0], wh[0], g);
      a0 = fmaf(hu[1], wh[1], a0);
      a0 = fmaf(hu[2], wh[2], a0);
      a0 = fmaf(hu[3], wh[3], a0);
      float a1 = hu[4] * wh[4];
      a1 = fmaf(hu[5], wh[5], a1);
      a1 = fmaf(hu[6], wh[6], a1);
      a1 = fmaf(hu[7], wh[7], a1);
      float a2 = hu[8] * wh[8];
      a2 = fmaf(hu[9], wh[9], a2);
      a2 = fmaf(hu[10], wh[10], a2);
      a2 = fmaf(hu[11], wh[11], a2);
      float a3 = hu[12] * wh[12];
      a3 = fmaf(hu[13], wh[13], a3);
      a3 = fmaf(hu[14], wh[14], a3);
      a3 = fmaf(hu[15], wh[15], a3);
      float gv_ = (a0 + a1) + (a2 + a3);

      // sigmoid: 1/(1+exp2(-L2E*g)); tanh: 2/(1+exp2(-2*L2E*g)) - 1
      float e = exp2f(gv_ * gscale);
      float s = __builtin_amdgcn_rcpf(1.0f + e);
      float act = is_tanh ? (2.0f * s - 1.0f) : s;

      float iv = __shfl(act, k);
      float fv = __shfl(act, k + 16);
      float gg = __shfl(act, k + 32);
      float ov = __shfl(act, k + 48);

      c = fmaf(fv, c, iv * gg);
      float e2 = exp2f(-2.0f * L2E * c);
      float tc = fmaf(2.0f, __builtin_amdgcn_rcpf(1.0f + e2), -1.0f);
      float hnew = ov * tc;

      if (lane < 16) hsm[tstep * HH + lane] = hnew;

#pragma unroll
      for (int kk = 0; kk < 16; kk++)
        hu[kk] = __uint_as_float(__builtin_amdgcn_readlane(__float_as_uint(hnew), kk));

      g = gnext;
    }
  }
  __syncthreads();

  // ---- Phase 3: output projection ----
  float* outb = out + (size_t)b * TT * CC;
  for (int idx = t; idx < TT * CC; idx += 256) {
    int tt = idx / CC;
    int cc = idx - tt * CC;
    const float* wr = W_out + cc * HH;
    float accv = b_out[cc];
#pragma unroll
    for (int kk = 0; kk < 16; kk++) accv = fmaf(hsm[tt * HH + kk], wr[kk], accv);
    outb[idx] = accv;
  }
}

// ---------------------------------------------------------------------------
extern "C" void kernel_launch(void* const* d_in, const int* in_sizes, int n_in,
                              void* d_out, int out_size, void* d_ws, size_t ws_size,
                              hipStream_t stream) {
  const int*   x     = (const int*)d_in[0];
  const float* emb   = (const float*)d_in[1];
  const float* W_ih  = (const float*)d_in[2];
  const float* W_hh  = (const float*)d_in[3];
  const float* b_ih  = (const float*)d_in[4];
  const float* b_hh  = (const float*)d_in[5];
  const float* W_out = (const float*)d_in[6];
  const float* b_out = (const float*)d_in[7];
  float* out = (float*)d_out;

  lstm_fused_kernel<<<BB, 256, 0, stream>>>(x, emb, W_ih, W_hh, b_ih, b_hh,
                                            W_out, b_out, out);
}

// Round 4
// 217.320 us; speedup vs baseline: 1.0883x; 1.0883x over previous
//
#include <hip/hip_runtime.h>
#include <cstdint>

// Problem constants
#define BB 256
#define TT 128
#define DD 300
#define HH 16
#define GG 64    // 4*H
#define CC 5
#define KC 60    // K-chunk (5 chunks of 60 cover D=300)

// ---------------------------------------------------------------------------
// Kernel 1: xg[row,c] = sum_d emb[x[row],d] * W_ih[c,d] (+bias later in k2? no,
// bias folded here). 512 blocks x 256 threads; tile 64 rows x 64 cols.
// A staged [row][d] (stride 60). W staged transposed [d][col] with XOR quad
// swizzle: physical col-quad = (c>>2) ^ (d>>2 within chunk)  -> conflict-free
// scalar transpose stores AND conflict-free b128 reads.
// Register-pipelined: load chunk k+1 into regs while computing chunk k.
// ---------------------------------------------------------------------------
__global__ __launch_bounds__(256) void xg_gemm_kernel(
    const int* __restrict__ x, const float* __restrict__ emb,
    const float* __restrict__ W_ih, const float* __restrict__ b_ih,
    const float* __restrict__ b_hh, float* __restrict__ xg) {

  __shared__ float As[64 * KC];   // 15.36 KB [row][d_local]
  __shared__ float Ws[KC * 64];   // 15.36 KB [d_local][col], XOR-swizzled quads
  __shared__ int   xid[64];

  const int t  = threadIdx.x;
  const int tx = t & 15;   // col quad: logical cols 4tx..4tx+3
  const int ty = t >> 4;   // row quad: rows 4ty..4ty+3
  const int row0 = blockIdx.x * 64;

  if (t < 64) xid[t] = x[row0 + t];
  __syncthreads();

  // Staging quotas: 64*15 = 960 float4 units for each of A and W.
  const int na = (t < 192) ? 4 : 3;

  float4 apf[4], wpf[4];

  auto load_chunk = [&](int dbase) {
#pragma unroll
    for (int i = 0; i < 4; i++) {
      if (i < na) {
        int u = t + 256 * i;
        int r = u / 15, f = u - r * 15;
        apf[i] = *(const float4*)(emb + (size_t)xid[r] * DD + dbase + 4 * f);
      }
    }
#pragma unroll
    for (int i = 0; i < 4; i++) {
      if (i < na) {
        int u = t + 256 * i;
        int c = u / 15, f = u - c * 15;
        wpf[i] = *(const float4*)(W_ih + c * DD + dbase + 4 * f);
      }
    }
  };

  auto store_chunk = [&]() {
#pragma unroll
    for (int i = 0; i < 4; i++) {
      if (i < na) {
        int u = t + 256 * i;
        int r = u / 15, f = u - r * 15;
        *(float4*)&As[r * KC + 4 * f] = apf[i];
      }
    }
#pragma unroll
    for (int i = 0; i < 4; i++) {
      if (i < na) {
        int u = t + 256 * i;
        int c = u / 15, f = u - c * 15;
        // physical col = ((cq ^ f) << 2) | (c & 3); rows d = 4f+j
        int cp = (((c >> 2) ^ f) << 2) | (c & 3);
        const float* w = (const float*)&wpf[i];
        Ws[(4 * f + 0) * 64 + cp] = w[0];
        Ws[(4 * f + 1) * 64 + cp] = w[1];
        Ws[(4 * f + 2) * 64 + cp] = w[2];
        Ws[(4 * f + 3) * 64 + cp] = w[3];
      }
    }
  };

  float acc[4][4] = {};

  load_chunk(0);
  for (int ch = 0; ch < 5; ch++) {
    if (ch > 0) __syncthreads();   // prior compute done; LDS reusable
    store_chunk();
    __syncthreads();               // staged data visible
    if (ch + 1 < 5) load_chunk((ch + 1) * KC);

#pragma unroll
    for (int q = 0; q < 15; q++) {
      float4 wc[4];
#pragma unroll
      for (int j = 0; j < 4; j++)
        wc[j] = *(const float4*)&Ws[(4 * q + j) * 64 + ((tx ^ q) << 2)];
      // ((float*)&wc[j])[m] = W_ih[col 4tx+m][k = 4q+j]
#pragma unroll
      for (int r = 0; r < 4; r++) {
        float4 a = *(const float4*)&As[(4 * ty + r) * KC + 4 * q];
#pragma unroll
        for (int m = 0; m < 4; m++) {
          acc[r][m] = fmaf(a.x, ((const float*)&wc[0])[m], acc[r][m]);
          acc[r][m] = fmaf(a.y, ((const float*)&wc[1])[m], acc[r][m]);
          acc[r][m] = fmaf(a.z, ((const float*)&wc[2])[m], acc[r][m]);
          acc[r][m] = fmaf(a.w, ((const float*)&wc[3])[m], acc[r][m]);
        }
      }
    }
  }

  float bias[4];
#pragma unroll
  for (int m = 0; m < 4; m++)
    bias[m] = b_ih[4 * tx + m] + b_hh[4 * tx + m];

#pragma unroll
  for (int r = 0; r < 4; r++) {
    float4 o;
    o.x = acc[r][0] + bias[0];
    o.y = acc[r][1] + bias[1];
    o.z = acc[r][2] + bias[2];
    o.w = acc[r][3] + bias[3];
    *(float4*)&xg[(size_t)(row0 + 4 * ty + r) * GG + 4 * tx] = o;
  }
}

// ---------------------------------------------------------------------------
// Kernel 2: LSTM recurrence + projection. 256 blocks x 64 threads,
// 40KB LDS -> 4 blocks/CU, one serial recurrence per SIMD.
// Lane map: k = lane>>2, gate = lane&3  -> gate exchange via DPP quad_perm
// (VALU latency) instead of ds_bpermute. Slab staged in 32-step chunks,
// register double-buffered behind the recurrence.
// ---------------------------------------------------------------------------
__global__ __launch_bounds__(64) void lstm_seq_kernel(
    const float* __restrict__ xg, const float* __restrict__ W_hh,
    const float* __restrict__ W_out, const float* __restrict__ b_out,
    float* __restrict__ out) {

  __shared__ float xgs[TT * GG];   // 32 KB
  __shared__ float hsm[TT * HH];   // 8 KB

  const int lane = threadIdx.x;
  const int b = blockIdx.x;
  const float4* __restrict__ src4 = (const float4*)(xg + (size_t)b * TT * GG);
  float4* dst4 = (float4*)xgs;

  const int k = lane >> 2;
  const int g = lane & 3;
  const int j = g * 16 + k;        // this lane's gate-row in W_hh / xg

  float wh[16];
  {
    const float* wr = W_hh + j * HH;
#pragma unroll
    for (int kk = 0; kk < 16; kk++) wh[kk] = wr[kk];
  }

  // Stage chunk 0 (steps 0..31 = 512 float4)
  float4 buf[8];
#pragma unroll
  for (int i = 0; i < 8; i++) buf[i] = src4[i * 64 + lane];
#pragma unroll
  for (int i = 0; i < 8; i++) dst4[i * 64 + lane] = buf[i];

  const float L2E = 1.4426950408889634f;
  const bool is_tanh = (g == 2);
  const float gscale = is_tanh ? (-2.0f * L2E) : (-L2E);

  float c = 0.0f;
  float hu[16];
#pragma unroll
  for (int kk = 0; kk < 16; kk++) hu[kk] = 0.0f;

  for (int ch = 0; ch < 4; ch++) {
    // Prefetch next chunk into registers (hidden under 32 recurrence steps)
    if (ch < 3) {
#pragma unroll
      for (int i = 0; i < 8; i++)
        buf[i] = src4[(ch + 1) * 512 + i * 64 + lane];
    }

    float gp = xgs[(ch * 32) * GG + j];
#pragma unroll 4
    for (int s = 0; s < 32; s++) {
      const int ts = ch * 32 + s;
      float gn = (s < 31) ? xgs[(ts + 1) * GG + j] : 0.0f;

      // g += h . W_hh[j,:]  (4 split accumulator chains)
      float a0 = fmaf(hu[0], wh[0], gp);
      a0 = fmaf(hu[1], wh[1], a0);
      a0 = fmaf(hu[2], wh[2], a0);
      a0 = fmaf(hu[3], wh[3], a0);
      float a1 = hu[4] * wh[4];
      a1 = fmaf(hu[5], wh[5], a1);
      a1 = fmaf(hu[6], wh[6], a1);
      a1 = fmaf(hu[7], wh[7], a1);
      float a2 = hu[8] * wh[8];
      a2 = fmaf(hu[9], wh[9], a2);
      a2 = fmaf(hu[10], wh[10], a2);
      a2 = fmaf(hu[11], wh[11], a2);
      float a3 = hu[12] * wh[12];
      a3 = fmaf(hu[13], wh[13], a3);
      a3 = fmaf(hu[14], wh[14], a3);
      a3 = fmaf(hu[15], wh[15], a3);
      float gv = (a0 + a1) + (a2 + a3);

      // sigmoid / tanh via exp2 + rcp (saturates correctly)
      float e = exp2f(gv * gscale);
      float sg = __builtin_amdgcn_rcpf(1.0f + e);
      float act = is_tanh ? fmaf(2.0f, sg, -1.0f) : sg;

      // Gate exchange within quad via DPP quad_perm broadcasts
      int ai = __float_as_int(act);
      float iv = __int_as_float(__builtin_amdgcn_update_dpp(ai, ai, 0x00, 0xF, 0xF, true));
      float fv = __int_as_float(__builtin_amdgcn_update_dpp(ai, ai, 0x55, 0xF, 0xF, true));
      float gg = __int_as_float(__builtin_amdgcn_update_dpp(ai, ai, 0xAA, 0xF, 0xF, true));
      float ov = __int_as_float(__builtin_amdgcn_update_dpp(ai, ai, 0xFF, 0xF, 0xF, true));

      c = fmaf(fv, c, iv * gg);
      float e2 = exp2f(-2.0f * L2E * c);
      float tc = fmaf(2.0f, __builtin_amdgcn_rcpf(1.0f + e2), -1.0f);
      float hnew = ov * tc;

      if (g == 0) hsm[ts * HH + k] = hnew;

      // Broadcast h: lanes 4*kk (gate 0 of quad kk) hold h_kk
#pragma unroll
      for (int kk = 0; kk < 16; kk++)
        hu[kk] = __uint_as_float(
            __builtin_amdgcn_readlane(__float_as_uint(hnew), 4 * kk));

      gp = gn;
    }

    // Store prefetched chunk (consumed starting next iteration)
    if (ch < 3) {
#pragma unroll
      for (int i = 0; i < 8; i++)
        dst4[(ch + 1) * 512 + i * 64 + lane] = buf[i];
    }
  }

  // Output projection: 640 outputs = 10 per lane
  float* outb = out + (size_t)b * TT * CC;
#pragma unroll
  for (int ii = 0; ii < 10; ii++) {
    int idx = ii * 64 + lane;
    int tt = idx / CC;
    int cc = idx - tt * CC;
    const float* wr = W_out + cc * HH;
    float accv = b_out[cc];
#pragma unroll
    for (int kk = 0; kk < 16; kk++)
      accv = fmaf(hsm[tt * HH + kk], wr[kk], accv);
    outb[idx] = accv;
  }
}

// ---------------------------------------------------------------------------
extern "C" void kernel_launch(void* const* d_in, const int* in_sizes, int n_in,
                              void* d_out, int out_size, void* d_ws, size_t ws_size,
                              hipStream_t stream) {
  const int*   x     = (const int*)d_in[0];
  const float* emb   = (const float*)d_in[1];
  const float* W_ih  = (const float*)d_in[2];
  const float* W_hh  = (const float*)d_in[3];
  const float* b_ih  = (const float*)d_in[4];
  const float* b_hh  = (const float*)d_in[5];
  const float* W_out = (const float*)d_in[6];
  const float* b_out = (const float*)d_in[7];
  float* out = (float*)d_out;
  float* xg  = (float*)d_ws;   // 32768 x 64 fp32 = 8.4 MB scratch

  xg_gemm_kernel<<<BB * TT / 64, 256, 0, stream>>>(x, emb, W_ih, b_ih, b_hh, xg);
  lstm_seq_kernel<<<BB, 64, 0, stream>>>(xg, W_hh, W_out, b_out, out);
}

// Round 5
// 211.398 us; speedup vs baseline: 1.1188x; 1.0280x over previous
//
#include <hip/hip_runtime.h>
#include <cstdint>

// Problem constants
#define BB 256
#define TT 128
#define DD 300
#define HH 16
#define GG 64    // 4*H
#define CC 5
#define NKS 10   // K-steps of 32 (300 padded to 320)

typedef __attribute__((ext_vector_type(8))) short short8;   // bf16x8 MFMA frag
typedef __attribute__((ext_vector_type(4))) float float4v;  // fp32x4 acc

// RNE fp32 -> bf16 bits
static __device__ inline unsigned short f2bf(float f) {
  unsigned u = __float_as_uint(f);
  unsigned r = (u + 0x7FFFu + ((u >> 16) & 1u)) >> 16;
  return (unsigned short)r;
}
static __device__ inline float bf2f(unsigned short h) {
  return __uint_as_float(((unsigned)h) << 16);
}

// ---------------------------------------------------------------------------
// Kernel 0: precompute W_ih hi/lo bf16 B-fragments in MFMA operand order.
// Frag layout (16x16x32 B-operand): lane holds B[k = quad*8+j][n = lane&15].
// Buffer index: ((ks*4 + nt)*64 + lane)*8 + j   (16B per lane -> coalesced).
// Grid: 40 blocks (ks*4+nt) x 64 lanes.
// ---------------------------------------------------------------------------
__global__ __launch_bounds__(64) void w_prep_kernel(
    const float* __restrict__ W_ih, unsigned short* __restrict__ Bh,
    unsigned short* __restrict__ Bl) {
  const int blk = blockIdx.x;
  const int ks = blk >> 2, nt = blk & 3;
  const int lane = threadIdx.x;
  const int n = lane & 15, quad = lane >> 4;
  const int c = nt * 16 + n;

  unsigned short h8[8], l8[8];
#pragma unroll
  for (int j = 0; j < 8; j++) {
    int k = ks * 32 + quad * 8 + j;
    float v = (k < DD) ? W_ih[c * DD + k] : 0.0f;
    unsigned short hb = f2bf(v);
    float rem = v - bf2f(hb);   // exact (Sterbenz)
    h8[j] = hb;
    l8[j] = f2bf(rem);
  }
  size_t base = ((size_t)blk * 64 + lane) * 8;
#pragma unroll
  for (int j = 0; j < 8; j++) { Bh[base + j] = h8[j]; Bl[base + j] = l8[j]; }
}

// ---------------------------------------------------------------------------
// Kernel 1: xg = gather(emb, x) @ W_ih^T + bias via split-bf16 MFMA.
// 512 blocks x 256 thr. Block covers 64 rows; wave w -> mtile rows
// row0+16w..+15, all 4 ntiles (64 cols). NO LDS, NO barriers.
// A-frag: lane m=lane&15 reads emb[x[r]][ks*32 + quad*8 .. +7] (2x dwordx4),
// split into hi/lo bf16 in registers. B-frags: coalesced 16B loads from the
// prepped buffers (L2-hot). acc += Ah*Bh + Al*Bh + Ah*Bl  (~2^-16 rel error).
// C/D layout: col=lane&15, row=quad*4+reg  [m89-verified].
// ---------------------------------------------------------------------------
__global__ __launch_bounds__(256) void xg_mfma_kernel(
    const int* __restrict__ x, const float* __restrict__ emb,
    const unsigned short* __restrict__ Bh, const unsigned short* __restrict__ Bl,
    const float* __restrict__ b_ih, const float* __restrict__ b_hh,
    float* __restrict__ xg) {

  const int t = threadIdx.x;
  const int w = t >> 6;
  const int lane = t & 63;
  const int m = lane & 15, quad = lane >> 4;
  const int row0 = blockIdx.x * 64;
  const int r = row0 + w * 16 + m;

  const int xr = x[r];
  const float* __restrict__ arow = emb + (size_t)xr * DD + quad * 8;

  float4v acc[4];
#pragma unroll
  for (int nt = 0; nt < 4; nt++) acc[nt] = (float4v){0.f, 0.f, 0.f, 0.f};

#pragma unroll
  for (int ks = 0; ks < NKS; ks++) {
    // ---- A: 8 consecutive fp32 from this lane's emb row ----
    float af[8];
    if (ks < 9) {
      float4 a0 = *(const float4*)(arow + ks * 32);
      float4 a1 = *(const float4*)(arow + ks * 32 + 4);
      af[0] = a0.x; af[1] = a0.y; af[2] = a0.z; af[3] = a0.w;
      af[4] = a1.x; af[5] = a1.y; af[6] = a1.z; af[7] = a1.w;
    } else {
      // k0 = 288 + quad*8; each dwordx4 is fully valid (k0+4<=300) or all-zero
      int k0 = 288 + quad * 8;
      float4 a0 = (k0 + 4 <= DD) ? *(const float4*)(arow + ks * 32)
                                 : (float4){0.f, 0.f, 0.f, 0.f};
      float4 a1 = (k0 + 8 <= DD) ? *(const float4*)(arow + ks * 32 + 4)
                                 : (float4){0.f, 0.f, 0.f, 0.f};
      af[0] = a0.x; af[1] = a0.y; af[2] = a0.z; af[3] = a0.w;
      af[4] = a1.x; af[5] = a1.y; af[6] = a1.z; af[7] = a1.w;
    }

    // Split into hi/lo bf16 fragments
    short8 ah, al;
#pragma unroll
    for (int j = 0; j < 8; j++) {
      unsigned short hb = f2bf(af[j]);
      ah[j] = (short)hb;
      al[j] = (short)f2bf(af[j] - bf2f(hb));
    }

    // ---- B frags + 3-product MFMA accumulate ----
#pragma unroll
    for (int nt = 0; nt < 4; nt++) {
      size_t fo = ((size_t)(ks * 4 + nt) * 64 + lane) * 8;
      short8 bh = *(const short8*)(Bh + fo);
      short8 bl = *(const short8*)(Bl + fo);
      acc[nt] = __builtin_amdgcn_mfma_f32_16x16x32_bf16(ah, bh, acc[nt], 0, 0, 0);
      acc[nt] = __builtin_amdgcn_mfma_f32_16x16x32_bf16(al, bh, acc[nt], 0, 0, 0);
      acc[nt] = __builtin_amdgcn_mfma_f32_16x16x32_bf16(ah, bl, acc[nt], 0, 0, 0);
    }
  }

  // ---- Epilogue: bias + store. Lane writes rows quad*4+reg, col nt*16+m ----
#pragma unroll
  for (int nt = 0; nt < 4; nt++) {
    int col = nt * 16 + m;
    float bias = b_ih[col] + b_hh[col];
#pragma unroll
    for (int reg = 0; reg < 4; reg++) {
      int rs = row0 + w * 16 + quad * 4 + reg;
      xg[(size_t)rs * GG + col] = acc[nt][reg] + bias;
    }
  }
}

// ---------------------------------------------------------------------------
// Kernel 2: LSTM recurrence + projection (unchanged from R4).
// 256 blocks x 64 threads; DPP quad_perm gate exchange; readlane h-broadcast.
// ---------------------------------------------------------------------------
__global__ __launch_bounds__(64) void lstm_seq_kernel(
    const float* __restrict__ xg, const float* __restrict__ W_hh,
    const float* __restrict__ W_out, const float* __restrict__ b_out,
    float* __restrict__ out) {

  __shared__ float xgs[TT * GG];   // 32 KB
  __shared__ float hsm[TT * HH];   // 8 KB

  const int lane = threadIdx.x;
  const int b = blockIdx.x;
  const float4* __restrict__ src4 = (const float4*)(xg + (size_t)b * TT * GG);
  float4* dst4 = (float4*)xgs;

  const int k = lane >> 2;
  const int g = lane & 3;
  const int j = g * 16 + k;

  float wh[16];
  {
    const float* wr = W_hh + j * HH;
#pragma unroll
    for (int kk = 0; kk < 16; kk++) wh[kk] = wr[kk];
  }

  float4 buf[8];
#pragma unroll
  for (int i = 0; i < 8; i++) buf[i] = src4[i * 64 + lane];
#pragma unroll
  for (int i = 0; i < 8; i++) dst4[i * 64 + lane] = buf[i];

  const float L2E = 1.4426950408889634f;
  const bool is_tanh = (g == 2);
  const float gscale = is_tanh ? (-2.0f * L2E) : (-L2E);

  float c = 0.0f;
  float hu[16];
#pragma unroll
  for (int kk = 0; kk < 16; kk++) hu[kk] = 0.0f;

  for (int ch = 0; ch < 4; ch++) {
    if (ch < 3) {
#pragma unroll
      for (int i = 0; i < 8; i++)
        buf[i] = src4[(ch + 1) * 512 + i * 64 + lane];
    }

    float gp = xgs[(ch * 32) * GG + j];
#pragma unroll 4
    for (int s = 0; s < 32; s++) {
      const int ts = ch * 32 + s;
      float gn = (s < 31) ? xgs[(ts + 1) * GG + j] : 0.0f;

      float a0 = fmaf(hu[0], wh[0], gp);
      a0 = fmaf(hu[1], wh[1], a0);
      a0 = fmaf(hu[2], wh[2], a0);
      a0 = fmaf(hu[3], wh[3], a0);
      float a1 = hu[4] * wh[4];
      a1 = fmaf(hu[5], wh[5], a1);
      a1 = fmaf(hu[6], wh[6], a1);
      a1 = fmaf(hu[7], wh[7], a1);
      float a2 = hu[8] * wh[8];
      a2 = fmaf(hu[9], wh[9], a2);
      a2 = fmaf(hu[10], wh[10], a2);
      a2 = fmaf(hu[11], wh[11], a2);
      float a3 = hu[12] * wh[12];
      a3 = fmaf(hu[13], wh[13], a3);
      a3 = fmaf(hu[14], wh[14], a3);
      a3 = fmaf(hu[15], wh[15], a3);
      float gv = (a0 + a1) + (a2 + a3);

      float e = exp2f(gv * gscale);
      float sg = __builtin_amdgcn_rcpf(1.0f + e);
      float act = is_tanh ? fmaf(2.0f, sg, -1.0f) : sg;

      int ai = __float_as_int(act);
      float iv = __int_as_float(__builtin_amdgcn_update_dpp(ai, ai, 0x00, 0xF, 0xF, true));
      float fv = __int_as_float(__builtin_amdgcn_update_dpp(ai, ai, 0x55, 0xF, 0xF, true));
      float gg = __int_as_float(__builtin_amdgcn_update_dpp(ai, ai, 0xAA, 0xF, 0xF, true));
      float ov = __int_as_float(__builtin_amdgcn_update_dpp(ai, ai, 0xFF, 0xF, 0xF, true));

      c = fmaf(fv, c, iv * gg);
      float e2 = exp2f(-2.0f * L2E * c);
      float tc = fmaf(2.0f, __builtin_amdgcn_rcpf(1.0f + e2), -1.0f);
      float hnew = ov * tc;

      if (g == 0) hsm[ts * HH + k] = hnew;

#pragma unroll
      for (int kk = 0; kk < 16; kk++)
        hu[kk] = __uint_as_float(
            __builtin_amdgcn_readlane(__float_as_uint(hnew), 4 * kk));

      gp = gn;
    }

    if (ch < 3) {
#pragma unroll
      for (int i = 0; i < 8; i++)
        dst4[(ch + 1) * 512 + i * 64 + lane] = buf[i];
    }
  }

  float* outb = out + (size_t)b * TT * CC;
#pragma unroll
  for (int ii = 0; ii < 10; ii++) {
    int idx = ii * 64 + lane;
    int tt = idx / CC;
    int cc = idx - tt * CC;
    const float* wr = W_out + cc * HH;
    float accv = b_out[cc];
#pragma unroll
    for (int kk = 0; kk < 16; kk++)
      accv = fmaf(hsm[tt * HH + kk], wr[kk], accv);
    outb[idx] = accv;
  }
}

// ---------------------------------------------------------------------------
extern "C" void kernel_launch(void* const* d_in, const int* in_sizes, int n_in,
                              void* d_out, int out_size, void* d_ws, size_t ws_size,
                              hipStream_t stream) {
  const int*   x     = (const int*)d_in[0];
  const float* emb   = (const float*)d_in[1];
  const float* W_ih  = (const float*)d_in[2];
  const float* W_hh  = (const float*)d_in[3];
  const float* b_ih  = (const float*)d_in[4];
  const float* b_hh  = (const float*)d_in[5];
  const float* W_out = (const float*)d_in[6];
  const float* b_out = (const float*)d_in[7];
  float* out = (float*)d_out;

  // ws layout: xg [32768*64 f32] = 8.39 MB, then Bh/Bl frag buffers (40 KB each)
  float* xg = (float*)d_ws;
  unsigned short* Bh = (unsigned short*)((char*)d_ws + (size_t)BB * TT * GG * 4);
  unsigned short* Bl = Bh + NKS * 4 * 64 * 8;

  w_prep_kernel<<<NKS * 4, 64, 0, stream>>>(W_ih, Bh, Bl);
  xg_mfma_kernel<<<BB * TT / 64, 256, 0, stream>>>(x, emb, Bh, Bl, b_ih, b_hh, xg);
  lstm_seq_kernel<<<BB, 64, 0, stream>>>(xg, W_hh, W_out, b_out, out);
}

// Round 6
// 200.479 us; speedup vs baseline: 1.1798x; 1.0545x over previous
//
#include <hip/hip_runtime.h>
#include <cstdint>

// Problem constants
#define BB 256
#define TT 128
#define DD 300
#define HH 16
#define GG 64    // 4*H
#define CC 5
#define NKS 10   // K-steps of 32 (300 padded to 320)

typedef __attribute__((ext_vector_type(8))) short short8;   // bf16x8 MFMA frag
typedef __attribute__((ext_vector_type(4))) float float4v;  // fp32x4 acc

// RNE fp32 -> bf16 bits
static __device__ inline unsigned short f2bf(float f) {
  unsigned u = __float_as_uint(f);
  return (unsigned short)((u + 0x7FFFu + ((u >> 16) & 1u)) >> 16);
}
static __device__ inline float bf2f(unsigned short h) {
  return __uint_as_float(((unsigned)h) << 16);
}

#define L2E 1.4426950408889634f

// ---------------------------------------------------------------------------
// Fully fused LSTM: 256 blocks (1/CU, one batch element) x 256 threads.
// Phase 0: build W_ih hi/lo bf16 B-fragments in LDS (40 sets of (ks,nt)).
// Phase 1: xg = gather(emb,x) @ W_ih^T + bias via split-bf16 MFMA, written
//          directly to LDS, pre-scaled by the per-gate exp2 constant.
// Phase 2: wave 0 runs the 128-step recurrence (DPP gate exchange).
// Phase 3: all waves do the output projection.
// ---------------------------------------------------------------------------
__global__ __launch_bounds__(256) void lstm_fused_kernel(
    const int* __restrict__ x, const float* __restrict__ emb,
    const float* __restrict__ W_ih, const float* __restrict__ W_hh,
    const float* __restrict__ b_ih, const float* __restrict__ b_hh,
    const float* __restrict__ W_out, const float* __restrict__ b_out,
    float* __restrict__ out) {

  __shared__ unsigned short Bh[NKS * 4 * 64 * 8];  // 40 KB
  __shared__ unsigned short Bl[NKS * 4 * 64 * 8];  // 40 KB
  __shared__ float xgs[TT * GG];                   // 32 KB (pre-scaled)
  __shared__ float hsm[TT * HH];                   // 8 KB
  __shared__ int   xid[TT];

  const int t = threadIdx.x;
  const int b = blockIdx.x;
  const int w = t >> 6;
  const int lane = t & 63;
  const int m = lane & 15, quad = lane >> 4;

  if (t < TT) xid[t] = x[b * TT + t];

  // ---- Phase 0: build B-fragments. Wave w builds sets 10w..10w+9. ----
  // Frag layout (16x16x32 B): lane holds B[k=quad*8+j][n=lane&15], j=0..7.
#pragma unroll 2
  for (int si = 0; si < 10; si++) {
    const int s = w * 10 + si;
    const int ks = s >> 2, nt = s & 3;
    const int c = nt * 16 + m;
    const int k0 = ks * 32 + quad * 8;
    const float* wr = W_ih + c * DD + k0;
    float4 w0 = (k0 + 4 <= DD) ? *(const float4*)wr : (float4){0.f,0.f,0.f,0.f};
    float4 w1 = (k0 + 8 <= DD) ? *(const float4*)(wr + 4) : (float4){0.f,0.f,0.f,0.f};
    float wf[8] = {w0.x, w0.y, w0.z, w0.w, w1.x, w1.y, w1.z, w1.w};
    unsigned short h8[8], l8[8];
#pragma unroll
    for (int j = 0; j < 8; j++) {
      unsigned short hb = f2bf(wf[j]);
      h8[j] = hb;
      l8[j] = f2bf(wf[j] - bf2f(hb));
    }
    const int base = (s * 64 + lane) * 8;
    *(short8*)&Bh[base] = *(const short8*)h8;
    *(short8*)&Bl[base] = *(const short8*)l8;
  }
  __syncthreads();

  // ---- Phase 1: MFMA GEMM into xgs. Wave w: rows w*32 .. w*32+31. ----
  {
    float4v acc[2][4];
#pragma unroll
    for (int mt = 0; mt < 2; mt++)
#pragma unroll
      for (int nt = 0; nt < 4; nt++) acc[mt][nt] = (float4v){0.f,0.f,0.f,0.f};

    const float* arow0 = emb + (size_t)xid[w * 32 + m] * DD + quad * 8;
    const float* arow1 = emb + (size_t)xid[w * 32 + 16 + m] * DD + quad * 8;

#pragma unroll 2
    for (int ks = 0; ks < NKS; ks++) {
      const int k0 = ks * 32 + quad * 8;
      float4 z = {0.f, 0.f, 0.f, 0.f};
      float4 a00 = (k0 + 4 <= DD) ? *(const float4*)(arow0 + ks * 32) : z;
      float4 a01 = (k0 + 8 <= DD) ? *(const float4*)(arow0 + ks * 32 + 4) : z;
      float4 a10 = (k0 + 4 <= DD) ? *(const float4*)(arow1 + ks * 32) : z;
      float4 a11 = (k0 + 8 <= DD) ? *(const float4*)(arow1 + ks * 32 + 4) : z;

      short8 ah[2], al[2];
      {
        float af0[8] = {a00.x, a00.y, a00.z, a00.w, a01.x, a01.y, a01.z, a01.w};
        float af1[8] = {a10.x, a10.y, a10.z, a10.w, a11.x, a11.y, a11.z, a11.w};
#pragma unroll
        for (int j = 0; j < 8; j++) {
          unsigned short hb0 = f2bf(af0[j]);
          ah[0][j] = (short)hb0;
          al[0][j] = (short)f2bf(af0[j] - bf2f(hb0));
          unsigned short hb1 = f2bf(af1[j]);
          ah[1][j] = (short)hb1;
          al[1][j] = (short)f2bf(af1[j] - bf2f(hb1));
        }
      }

#pragma unroll
      for (int nt = 0; nt < 4; nt++) {
        const int base = ((ks * 4 + nt) * 64 + lane) * 8;
        short8 bh = *(const short8*)&Bh[base];
        short8 bl = *(const short8*)&Bl[base];
#pragma unroll
        for (int mt = 0; mt < 2; mt++) {
          acc[mt][nt] = __builtin_amdgcn_mfma_f32_16x16x32_bf16(ah[mt], bh, acc[mt][nt], 0, 0, 0);
          acc[mt][nt] = __builtin_amdgcn_mfma_f32_16x16x32_bf16(al[mt], bh, acc[mt][nt], 0, 0, 0);
          acc[mt][nt] = __builtin_amdgcn_mfma_f32_16x16x32_bf16(ah[mt], bl, acc[mt][nt], 0, 0, 0);
        }
      }
    }

    // Epilogue: bias + gate pre-scale, store to xgs.
    // C/D layout: col=lane&15, row=quad*4+reg  [m89-verified].
#pragma unroll
    for (int nt = 0; nt < 4; nt++) {
      const int col = nt * 16 + m;
      const float scale = (nt == 2) ? (-2.0f * L2E) : (-L2E);
      const float bias = b_ih[col] + b_hh[col];
#pragma unroll
      for (int mt = 0; mt < 2; mt++) {
        const int rbase = w * 32 + mt * 16 + quad * 4;
#pragma unroll
        for (int reg = 0; reg < 4; reg++)
          xgs[(rbase + reg) * GG + col] = (acc[mt][nt][reg] + bias) * scale;
      }
    }
  }
  __syncthreads();

  // ---- Phase 2: recurrence (wave 0). Lane: k=lane>>2, g=lane&3, j=g*16+k ----
  if (t < 64) {
    const int k = lane >> 2;
    const int g = lane & 3;
    const int j = g * 16 + k;
    const bool is_tanh = (g == 2);
    const float wscale = is_tanh ? (-2.0f * L2E) : (-L2E);

    float wh[16];
    {
      const float* wr = W_hh + j * HH;
#pragma unroll
      for (int kk = 0; kk < 16; kk++) wh[kk] = wr[kk] * wscale;
    }

    float c = 0.0f;
    float hu[16];
#pragma unroll
    for (int kk = 0; kk < 16; kk++) hu[kk] = 0.0f;

    float gp = xgs[j];
#pragma unroll 4
    for (int ts = 0; ts < TT; ts++) {
      float gn = xgs[((ts + 1) & 127) * GG + j];

      // gv = scaled preact + h . wh (4 split accumulator chains)
      float a0 = fmaf(hu[0], wh[0], gp);
      a0 = fmaf(hu[1], wh[1], a0);
      a0 = fmaf(hu[2], wh[2], a0);
      a0 = fmaf(hu[3], wh[3], a0);
      float a1 = hu[4] * wh[4];
      a1 = fmaf(hu[5], wh[5], a1);
      a1 = fmaf(hu[6], wh[6], a1);
      a1 = fmaf(hu[7], wh[7], a1);
      float a2 = hu[8] * wh[8];
      a2 = fmaf(hu[9], wh[9], a2);
      a2 = fmaf(hu[10], wh[10], a2);
      a2 = fmaf(hu[11], wh[11], a2);
      float a3 = hu[12] * wh[12];
      a3 = fmaf(hu[13], wh[13], a3);
      a3 = fmaf(hu[14], wh[14], a3);
      a3 = fmaf(hu[15], wh[15], a3);
      float gv = (a0 + a1) + (a2 + a3);

      float e = exp2f(gv);                       // pre-scaled: no mult on chain
      float sg = __builtin_amdgcn_rcpf(1.0f + e);
      float act = is_tanh ? fmaf(2.0f, sg, -1.0f) : sg;

      int ai = __float_as_int(act);
      float iv = __int_as_float(__builtin_amdgcn_update_dpp(ai, ai, 0x00, 0xF, 0xF, true));
      float fv = __int_as_float(__builtin_amdgcn_update_dpp(ai, ai, 0x55, 0xF, 0xF, true));
      float gg = __int_as_float(__builtin_amdgcn_update_dpp(ai, ai, 0xAA, 0xF, 0xF, true));
      float ov = __int_as_float(__builtin_amdgcn_update_dpp(ai, ai, 0xFF, 0xF, 0xF, true));

      c = fmaf(fv, c, iv * gg);
      float e2 = exp2f(-2.0f * L2E * c);
      float tc = fmaf(2.0f, __builtin_amdgcn_rcpf(1.0f + e2), -1.0f);
      float hnew = ov * tc;

      if (g == 0) hsm[ts * HH + k] = hnew;

#pragma unroll
      for (int kk = 0; kk < 16; kk++)
        hu[kk] = __uint_as_float(
            __builtin_amdgcn_readlane(__float_as_uint(hnew), 4 * kk));

      gp = gn;
    }
  }
  __syncthreads();

  // ---- Phase 3: output projection ----
  float* outb = out + (size_t)b * TT * CC;
  for (int idx = t; idx < TT * CC; idx += 256) {
    int tt = idx / CC;
    int cc = idx - tt * CC;
    const float* wr = W_out + cc * HH;
    float accv = b_out[cc];
#pragma unroll
    for (int kk = 0; kk < 16; kk++)
      accv = fmaf(hsm[tt * HH + kk], wr[kk], accv);
    outb[idx] = accv;
  }
}

// ---------------------------------------------------------------------------
extern "C" void kernel_launch(void* const* d_in, const int* in_sizes, int n_in,
                              void* d_out, int out_size, void* d_ws, size_t ws_size,
                              hipStream_t stream) {
  const int*   x     = (const int*)d_in[0];
  const float* emb   = (const float*)d_in[1];
  const float* W_ih  = (const float*)d_in[2];
  const float* W_hh  = (const float*)d_in[3];
  const float* b_ih  = (const float*)d_in[4];
  const float* b_hh  = (const float*)d_in[5];
  const float* W_out = (const float*)d_in[6];
  const float* b_out = (const float*)d_in[7];
  float* out = (float*)d_out;

  lstm_fused_kernel<<<BB, 256, 0, stream>>>(x, emb, W_ih, W_hh, b_ih, b_hh,
                                            W_out, b_out, out);
}

// Round 7
// 198.204 us; speedup vs baseline: 1.1933x; 1.0115x over previous
//
#include <hip/hip_runtime.h>
#include <cstdint>

// Problem constants
#define BB 256
#define TT 128
#define DD 300
#define HH 16
#define GG 64     // 4*H
#define CC 5
#define NKS 10    // K-steps of 32 (300 padded to 320)
#define XSTR 132  // xgsT row stride in floats (16B-aligned, bank-skewed)
#define L2E 1.4426950408889634f

typedef __attribute__((ext_vector_type(8))) short short8;   // bf16x8 MFMA frag
typedef __attribute__((ext_vector_type(4))) float float4v;  // fp32x4 acc

// RNE fp32 -> bf16 bits
static __device__ inline unsigned short f2bf(float f) {
  unsigned u = __float_as_uint(f);
  return (unsigned short)((u + 0x7FFFu + ((u >> 16) & 1u)) >> 16);
}
static __device__ inline float bf2f(unsigned short h) {
  return __uint_as_float(((unsigned)h) << 16);
}

// ---------------------------------------------------------------------------
// Fully fused LSTM: 256 blocks (1/CU, one batch element) x 256 threads.
//   pre : issue all emb gather loads (latency hides under phase 0)
//   ph0 : coalesced W_ih copy -> LDS, then build hi/lo bf16 B-frags from LDS
//   ph1 : split-bf16 MFMA GEMM -> xgsT (transposed, pre-scaled, in LDS)
//   ph2 : wave 0: 128-step recurrence, scaled-c domain, DPP gate exchange,
//         one ds_read_b128 per 4 steps (prefetched 8 steps ahead)
//   ph3 : output projection
// LDS: Bh 40K + Bl 40K + union{rawW 75.25K | xgsT 33K + hsm 32K} = 159.5 KB
// ---------------------------------------------------------------------------
__global__ __launch_bounds__(256, 1) void lstm_fused_kernel(
    const int* __restrict__ x, const float* __restrict__ emb,
    const float* __restrict__ W_ih, const float* __restrict__ W_hh,
    const float* __restrict__ b_ih, const float* __restrict__ b_hh,
    const float* __restrict__ W_out, const float* __restrict__ b_out,
    float* __restrict__ out) {

  __shared__ unsigned short Bh[NKS * 4 * 64 * 8];  // 40 KB
  __shared__ unsigned short Bl[NKS * 4 * 64 * 8];  // 40 KB
  __shared__ float uni[19264];                     // 75.25 KB union region

  float* rawW = uni;                 // ph0: W_ih raw copy [64][300]
  float* xgsT = uni;                 // ph1/2: [64 gates][XSTR] transposed preacts
  float* hsm  = uni + GG * XSTR;     // ph2/3: [128][64] hidden states

  const int t = threadIdx.x;
  const int b = blockIdx.x;
  const int w = t >> 6;
  const int lane = t & 63;
  const int m = lane & 15, quad = lane >> 4;

  // ---- Pre-issue ALL emb gather loads (hide latency under phase 0) ----
  const int xr0 = x[b * TT + w * 32 + m];
  const int xr1 = x[b * TT + w * 32 + 16 + m];
  const float* __restrict__ arow0 = emb + (size_t)xr0 * DD + quad * 8;
  const float* __restrict__ arow1 = emb + (size_t)xr1 * DD + quad * 8;

  float4 ld[2][NKS][2];
#pragma unroll
  for (int ks = 0; ks < 9; ks++) {
    ld[0][ks][0] = *(const float4*)(arow0 + ks * 32);
    ld[0][ks][1] = *(const float4*)(arow0 + ks * 32 + 4);
    ld[1][ks][0] = *(const float4*)(arow1 + ks * 32);
    ld[1][ks][1] = *(const float4*)(arow1 + ks * 32 + 4);
  }
  {
    const int k0t = 288 + quad * 8;
    float4 z4 = {0.f, 0.f, 0.f, 0.f};
    ld[0][9][0] = (k0t + 4 <= DD) ? *(const float4*)(arow0 + 288) : z4;
    ld[0][9][1] = (k0t + 8 <= DD) ? *(const float4*)(arow0 + 292) : z4;
    ld[1][9][0] = (k0t + 4 <= DD) ? *(const float4*)(arow1 + 288) : z4;
    ld[1][9][1] = (k0t + 8 <= DD) ? *(const float4*)(arow1 + 292) : z4;
  }

  // ---- Phase 0a: coalesced W_ih copy -> rawW (19200 floats = 4800 float4) ----
  {
    const float4* __restrict__ src = (const float4*)W_ih;
    float4* dst = (float4*)rawW;
#pragma unroll
    for (int i = 0; i < 18; i++) dst[t + 256 * i] = src[t + 256 * i];
    if (t < 192) dst[t + 256 * 18] = src[t + 256 * 18];
  }
  __syncthreads();

  // ---- Phase 0b: build B-frags from rawW. Wave w builds sets 10w..10w+9. ----
  // Frag layout (16x16x32 B): lane holds B[k=quad*8+j][n=lane&15], j=0..7.
  for (int si = 0; si < 10; si++) {
    const int s = w * 10 + si;
    const int ks = s >> 2, nt = s & 3;
    const int c = nt * 16 + m;
    const int k0 = ks * 32 + quad * 8;
    float4 z4 = {0.f, 0.f, 0.f, 0.f};
    float4 w0 = z4, w1 = z4;
    if (k0 + 4 <= DD) w0 = *(const float4*)&rawW[c * DD + k0];
    if (k0 + 8 <= DD) w1 = *(const float4*)&rawW[c * DD + k0 + 4];
    float wf[8] = {w0.x, w0.y, w0.z, w0.w, w1.x, w1.y, w1.z, w1.w};
    short8 h8, l8;
#pragma unroll
    for (int jj = 0; jj < 8; jj++) {
      unsigned short hb = f2bf(wf[jj]);
      h8[jj] = (short)hb;
      l8[jj] = (short)f2bf(wf[jj] - bf2f(hb));
    }
    const int base = (s * 64 + lane) * 8;
    *(short8*)&Bh[base] = h8;
    *(short8*)&Bl[base] = l8;
  }
  __syncthreads();   // frags ready; rawW dead -> xgsT/hsm may be written

  // ---- Phase 1: MFMA GEMM. Wave w covers timestep-rows w*32..w*32+31. ----
  {
    float4v acc[2][4];
#pragma unroll
    for (int mt = 0; mt < 2; mt++)
#pragma unroll
      for (int nt = 0; nt < 4; nt++) acc[mt][nt] = (float4v){0.f, 0.f, 0.f, 0.f};

#pragma unroll
    for (int ks = 0; ks < NKS; ks++) {
      short8 ah[2], al[2];
#pragma unroll
      for (int mt = 0; mt < 2; mt++) {
        float af[8] = {ld[mt][ks][0].x, ld[mt][ks][0].y, ld[mt][ks][0].z,
                       ld[mt][ks][0].w, ld[mt][ks][1].x, ld[mt][ks][1].y,
                       ld[mt][ks][1].z, ld[mt][ks][1].w};
#pragma unroll
        for (int jj = 0; jj < 8; jj++) {
          unsigned short hb = f2bf(af[jj]);
          ah[mt][jj] = (short)hb;
          al[mt][jj] = (short)f2bf(af[jj] - bf2f(hb));
        }
      }
#pragma unroll
      for (int nt = 0; nt < 4; nt++) {
        const int base = ((ks * 4 + nt) * 64 + lane) * 8;
        short8 bh = *(const short8*)&Bh[base];
        short8 bl = *(const short8*)&Bl[base];
#pragma unroll
        for (int mt = 0; mt < 2; mt++) {
          acc[mt][nt] = __builtin_amdgcn_mfma_f32_16x16x32_bf16(ah[mt], bh, acc[mt][nt], 0, 0, 0);
          acc[mt][nt] = __builtin_amdgcn_mfma_f32_16x16x32_bf16(al[mt], bh, acc[mt][nt], 0, 0, 0);
          acc[mt][nt] = __builtin_amdgcn_mfma_f32_16x16x32_bf16(ah[mt], bl, acc[mt][nt], 0, 0, 0);
        }
      }
    }

    // Epilogue: bias + per-gate pre-scale, TRANSPOSED store: xgsT[gate][ts].
    // C/D layout: col=lane&15, row=quad*4+reg  [m89-verified].
#pragma unroll
    for (int nt = 0; nt < 4; nt++) {
      const int col = nt * 16 + m;
      const float scale = (nt == 2) ? (-2.0f * L2E) : (-L2E);
      const float bias = b_ih[col] + b_hh[col];
#pragma unroll
      for (int mt = 0; mt < 2; mt++) {
#pragma unroll
        for (int reg = 0; reg < 4; reg++) {
          const int ts = w * 32 + mt * 16 + quad * 4 + reg;
          xgsT[col * XSTR + ts] = (acc[mt][nt][reg] + bias) * scale;
        }
      }
    }
  }
  __syncthreads();

  // ---- Phase 2: recurrence (wave 0). Lane: k=lane>>2, g=lane&3, j=g*16+k ----
  if (t < 64) {
    const int k = lane >> 2;
    const int g = lane & 3;
    const int j = g * 16 + k;
    const float wscale = (g == 2) ? (-2.0f * L2E) : (-L2E);
    const float Aa = (g == 2) ? (-4.0f * L2E) : 1.0f;   // act = Aa*s + Ba
    const float Ba = (g == 2) ? (2.0f * L2E) : 0.0f;    // gate2 -> scaled tanh

    float wh[16];
#pragma unroll
    for (int kk = 0; kk < 16; kk++) wh[kk] = W_hh[j * HH + kk] * wscale;

    float cs = 0.0f;   // scaled cell state: cs = -2*L2E*c
    float hu[16];
#pragma unroll
    for (int kk = 0; kk < 16; kk++) hu[kk] = 0.0f;

    const float* __restrict__ gptr = &xgsT[j * XSTR];
    float4 gA = *(const float4*)gptr;        // ts 0..3
    float4 gB = *(const float4*)(gptr + 4);  // ts 4..7

    for (int ch = 0; ch < 32; ch++) {
      float4 gC = (ch < 30) ? *(const float4*)(gptr + 4 * (ch + 2)) : gA;
      float ga[4] = {gA.x, gA.y, gA.z, gA.w};
#pragma unroll
      for (int s4 = 0; s4 < 4; s4++) {
        const int ts = ch * 4 + s4;
        // gv = scaled preact + h . wh  (4 split chains)
        float a0 = fmaf(hu[0], wh[0], ga[s4]);
        a0 = fmaf(hu[1], wh[1], a0);
        a0 = fmaf(hu[2], wh[2], a0);
        a0 = fmaf(hu[3], wh[3], a0);
        float a1 = hu[4] * wh[4];
        a1 = fmaf(hu[5], wh[5], a1);
        a1 = fmaf(hu[6], wh[6], a1);
        a1 = fmaf(hu[7], wh[7], a1);
        float a2 = hu[8] * wh[8];
        a2 = fmaf(hu[9], wh[9], a2);
        a2 = fmaf(hu[10], wh[10], a2);
        a2 = fmaf(hu[11], wh[11], a2);
        float a3 = hu[12] * wh[12];
        a3 = fmaf(hu[13], wh[13], a3);
        a3 = fmaf(hu[14], wh[14], a3);
        a3 = fmaf(hu[15], wh[15], a3);
        float gv = (a0 + a1) + (a2 + a3);

        float e = __builtin_amdgcn_exp2f(gv);
        float s = __builtin_amdgcn_rcpf(1.0f + e);
        float act = fmaf(Aa, s, Ba);   // sigmoid, or -2L2E*tanh for gate 2

        int ai = __float_as_int(act);
        float iv = __int_as_float(__builtin_amdgcn_update_dpp(ai, ai, 0x00, 0xF, 0xF, true));
        float fv = __int_as_float(__builtin_amdgcn_update_dpp(ai, ai, 0x55, 0xF, 0xF, true));
        float gs = __int_as_float(__builtin_amdgcn_update_dpp(ai, ai, 0xAA, 0xF, 0xF, true));
        float ov = __int_as_float(__builtin_amdgcn_update_dpp(ai, ai, 0xFF, 0xF, 0xF, true));

        cs = fmaf(fv, cs, iv * gs);    // scaled-domain cell update
        float e2 = __builtin_amdgcn_exp2f(cs);
        float tc = fmaf(2.0f, __builtin_amdgcn_rcpf(1.0f + e2), -1.0f);  // tanh(c)
        float hnew = ov * tc;          // quad-uniform

        hsm[ts * GG + lane] = hnew;    // all lanes store (no exec toggle)

#pragma unroll
        for (int kk = 0; kk < 16; kk++)
          hu[kk] = __uint_as_float(
              __builtin_amdgcn_readlane(__float_as_uint(hnew), 4 * kk));
      }
      gA = gB; gB = gC;
    }
  }
  __syncthreads();

  // ---- Phase 3: output projection ----
  float* outb = out + (size_t)b * TT * CC;
  for (int idx = t; idx < TT * CC; idx += 256) {
    int tt2 = idx / CC;
    int cc = idx - tt2 * CC;
    const float* wr = W_out + cc * HH;
    float accv = b_out[cc];
#pragma unroll
    for (int kk = 0; kk < 16; kk++)
      accv = fmaf(hsm[tt2 * GG + 4 * kk], wr[kk], accv);
    outb[idx] = accv;
  }
}

// ---------------------------------------------------------------------------
extern "C" void kernel_launch(void* const* d_in, const int* in_sizes, int n_in,
                              void* d_out, int out_size, void* d_ws, size_t ws_size,
                              hipStream_t stream) {
  const int*   x     = (const int*)d_in[0];
  const float* emb   = (const float*)d_in[1];
  const float* W_ih  = (const float*)d_in[2];
  const float* W_hh  = (const float*)d_in[3];
  const float* b_ih  = (const float*)d_in[4];
  const float* b_hh  = (const float*)d_in[5];
  const float* W_out = (const float*)d_in[6];
  const float* b_out = (const float*)d_in[7];
  float* out = (float*)d_out;

  lstm_fused_kernel<<<BB, 256, 0, stream>>>(x, emb, W_ih, W_hh, b_ih, b_hh,
                                            W_out, b_out, out);
}

// Round 8
// 196.763 us; speedup vs baseline: 1.2020x; 1.0073x over previous
//
#include <hip/hip_runtime.h>
#include <cstdint>

// Problem constants
#define BB 256
#define TT 128
#define DD 300
#define HH 16
#define GG 64     // 4*H
#define CC 5
#define NKS 10    // K-steps of 32 (300 padded to 320)
#define XSTR 132  // xgsT row stride in floats (16B-aligned, bank-skewed)
#define L2E 1.4426950408889634f

typedef __attribute__((ext_vector_type(8))) short short8;   // bf16x8 MFMA frag
typedef __attribute__((ext_vector_type(4))) float float4v;  // fp32x4 acc

// RNE fp32 -> bf16 bits
static __device__ inline unsigned short f2bf(float f) {
  unsigned u = __float_as_uint(f);
  return (unsigned short)((u + 0x7FFFu + ((u >> 16) & 1u)) >> 16);
}
static __device__ inline float bf2f(unsigned short h) {
  return __uint_as_float(((unsigned)h) << 16);
}

// ---------------------------------------------------------------------------
// Fully fused LSTM: 256 blocks (1/CU, one batch element) x 256 threads.
//   ph0 : coalesced W_ih copy -> LDS, build hi/lo bf16 B-frags from LDS
//   ph1 : split-bf16 MFMA GEMM -> xgsT (transposed, pre-scaled, in LDS)
//         A-gathers via depth-2 software pipeline (32 VGPR staging, NO spill)
//   ph2 : wave 0: 128-step recurrence, scaled-c domain, DPP gate exchange
//   ph3 : output projection
// LDS: Bh 40K + Bl 40K + union{rawW 75.25K | xgsT 33K + hsm 32K} = 155.25 KB
// ---------------------------------------------------------------------------
__global__ __launch_bounds__(256, 1) void lstm_fused_kernel(
    const int* __restrict__ x, const float* __restrict__ emb,
    const float* __restrict__ W_ih, const float* __restrict__ W_hh,
    const float* __restrict__ b_ih, const float* __restrict__ b_hh,
    const float* __restrict__ W_out, const float* __restrict__ b_out,
    float* __restrict__ out) {

  __shared__ unsigned short Bh[NKS * 4 * 64 * 8];  // 40 KB
  __shared__ unsigned short Bl[NKS * 4 * 64 * 8];  // 40 KB
  __shared__ float uni[19264];                     // 75.25 KB union region

  float* rawW = uni;                 // ph0: W_ih raw copy [64][300]
  float* xgsT = uni;                 // ph1/2: [64 gates][XSTR] transposed preacts
  float* hsm  = uni + GG * XSTR;     // ph2/3: [128][64] hidden states

  const int t = threadIdx.x;
  const int b = blockIdx.x;
  const int w = t >> 6;
  const int lane = t & 63;
  const int m = lane & 15, quad = lane >> 4;

  // ---- Phase 0a: coalesced W_ih copy -> rawW (19200 floats = 4800 float4) ----
  {
    const float4* __restrict__ src = (const float4*)W_ih;
    float4* dst = (float4*)rawW;
#pragma unroll
    for (int i = 0; i < 18; i++) dst[t + 256 * i] = src[t + 256 * i];
    if (t < 192) dst[t + 256 * 18] = src[t + 256 * 18];
  }
  __syncthreads();

  // ---- Phase 0b: build B-frags from rawW. Wave w builds sets 10w..10w+9. ----
  // Frag layout (16x16x32 B): lane holds B[k=quad*8+j][n=lane&15], j=0..7.
  for (int si = 0; si < 10; si++) {
    const int s = w * 10 + si;
    const int ks = s >> 2, nt = s & 3;
    const int c = nt * 16 + m;
    const int k0 = ks * 32 + quad * 8;
    float4 z4 = {0.f, 0.f, 0.f, 0.f};
    float4 w0 = z4, w1 = z4;
    if (k0 + 4 <= DD) w0 = *(const float4*)&rawW[c * DD + k0];
    if (k0 + 8 <= DD) w1 = *(const float4*)&rawW[c * DD + k0 + 4];
    float wf[8] = {w0.x, w0.y, w0.z, w0.w, w1.x, w1.y, w1.z, w1.w};
    short8 h8, l8;
#pragma unroll
    for (int jj = 0; jj < 8; jj++) {
      unsigned short hb = f2bf(wf[jj]);
      h8[jj] = (short)hb;
      l8[jj] = (short)f2bf(wf[jj] - bf2f(hb));
    }
    const int base = (s * 64 + lane) * 8;
    *(short8*)&Bh[base] = h8;
    *(short8*)&Bl[base] = l8;
  }
  __syncthreads();   // frags ready; rawW dead -> xgsT/hsm may be written

  // ---- Phase 1: MFMA GEMM. Wave w covers timestep-rows w*32..w*32+31. ----
  {
    const int xr0 = x[b * TT + w * 32 + m];
    const int xr1 = x[b * TT + w * 32 + 16 + m];
    const float* __restrict__ arow0 = emb + (size_t)xr0 * DD + quad * 8;
    const float* __restrict__ arow1 = emb + (size_t)xr1 * DD + quad * 8;

    float4v acc[2][4];
#pragma unroll
    for (int mt = 0; mt < 2; mt++)
#pragma unroll
      for (int nt = 0; nt < 4; nt++) acc[mt][nt] = (float4v){0.f, 0.f, 0.f, 0.f};

    // Depth-2 rolling prefetch: pre[parity][row][half] = 8 float4 = 32 VGPRs.
    float4 pre[2][2][2];
    auto issue = [&](int ks) {
      if (ks < 9) {
        const int p = ks & 1;
        pre[p][0][0] = *(const float4*)(arow0 + ks * 32);
        pre[p][0][1] = *(const float4*)(arow0 + ks * 32 + 4);
        pre[p][1][0] = *(const float4*)(arow1 + ks * 32);
        pre[p][1][1] = *(const float4*)(arow1 + ks * 32 + 4);
      } else if (ks == 9) {
        // Tail: k0 = 288 + quad*8; guard each float4 (no OOB reads on last row)
        const int k0t = 288 + quad * 8;
        float4 z4 = {0.f, 0.f, 0.f, 0.f};
        pre[1][0][0] = (k0t + 4 <= DD) ? *(const float4*)(arow0 + 288) : z4;
        pre[1][0][1] = (k0t + 8 <= DD) ? *(const float4*)(arow0 + 292) : z4;
        pre[1][1][0] = (k0t + 4 <= DD) ? *(const float4*)(arow1 + 288) : z4;
        pre[1][1][1] = (k0t + 8 <= DD) ? *(const float4*)(arow1 + 292) : z4;
      }
    };
    issue(0);
    issue(1);

#pragma unroll
    for (int ks = 0; ks < NKS; ks++) {
      const int p = ks & 1;
      // Consume: convert this ks's A data to hi/lo bf16 fragments.
      short8 ah[2], al[2];
#pragma unroll
      for (int mt = 0; mt < 2; mt++) {
        float af[8] = {pre[p][mt][0].x, pre[p][mt][0].y, pre[p][mt][0].z,
                       pre[p][mt][0].w, pre[p][mt][1].x, pre[p][mt][1].y,
                       pre[p][mt][1].z, pre[p][mt][1].w};
#pragma unroll
        for (int jj = 0; jj < 8; jj++) {
          unsigned short hb = f2bf(af[jj]);
          ah[mt][jj] = (short)hb;
          al[mt][jj] = (short)f2bf(af[jj] - bf2f(hb));
        }
      }
      // Re-issue this parity slot for ks+2 (no-op past the end).
      issue(ks + 2);

#pragma unroll
      for (int nt = 0; nt < 4; nt++) {
        const int base = ((ks * 4 + nt) * 64 + lane) * 8;
        short8 bh = *(const short8*)&Bh[base];
        short8 bl = *(const short8*)&Bl[base];
#pragma unroll
        for (int mt = 0; mt < 2; mt++) {
          acc[mt][nt] = __builtin_amdgcn_mfma_f32_16x16x32_bf16(ah[mt], bh, acc[mt][nt], 0, 0, 0);
          acc[mt][nt] = __builtin_amdgcn_mfma_f32_16x16x32_bf16(al[mt], bh, acc[mt][nt], 0, 0, 0);
          acc[mt][nt] = __builtin_amdgcn_mfma_f32_16x16x32_bf16(ah[mt], bl, acc[mt][nt], 0, 0, 0);
        }
      }
    }

    // Epilogue: bias + per-gate pre-scale, TRANSPOSED store: xgsT[gate][ts].
    // C/D layout: col=lane&15, row=quad*4+reg  [m89-verified].
#pragma unroll
    for (int nt = 0; nt < 4; nt++) {
      const int col = nt * 16 + m;
      const float scale = (nt == 2) ? (-2.0f * L2E) : (-L2E);
      const float bias = b_ih[col] + b_hh[col];
#pragma unroll
      for (int mt = 0; mt < 2; mt++) {
#pragma unroll
        for (int reg = 0; reg < 4; reg++) {
          const int ts = w * 32 + mt * 16 + quad * 4 + reg;
          xgsT[col * XSTR + ts] = (acc[mt][nt][reg] + bias) * scale;
        }
      }
    }
  }
  __syncthreads();

  // ---- Phase 2: recurrence (wave 0). Lane: k=lane>>2, g=lane&3, j=g*16+k ----
  if (t < 64) {
    const int k = lane >> 2;
    const int g = lane & 3;
    const int j = g * 16 + k;
    const float wscale = (g == 2) ? (-2.0f * L2E) : (-L2E);
    const float Aa = (g == 2) ? (-4.0f * L2E) : 1.0f;   // act = Aa*s + Ba
    const float Ba = (g == 2) ? (2.0f * L2E) : 0.0f;    // gate2 -> scaled tanh

    float wh[16];
#pragma unroll
    for (int kk = 0; kk < 16; kk++) wh[kk] = W_hh[j * HH + kk] * wscale;

    float cs = 0.0f;   // scaled cell state: cs = -2*L2E*c
    float hu[16];
#pragma unroll
    for (int kk = 0; kk < 16; kk++) hu[kk] = 0.0f;

    const float* __restrict__ gptr = &xgsT[j * XSTR];
    float4 gA = *(const float4*)gptr;        // ts 0..3
    float4 gB = *(const float4*)(gptr + 4);  // ts 4..7

    for (int ch = 0; ch < 32; ch++) {
      float4 gC = (ch < 30) ? *(const float4*)(gptr + 4 * (ch + 2)) : gA;
      float ga[4] = {gA.x, gA.y, gA.z, gA.w};
#pragma unroll
      for (int s4 = 0; s4 < 4; s4++) {
        const int ts = ch * 4 + s4;
        // gv = scaled preact + h . wh  (4 split chains)
        float a0 = fmaf(hu[0], wh[0], ga[s4]);
        a0 = fmaf(hu[1], wh[1], a0);
        a0 = fmaf(hu[2], wh[2], a0);
        a0 = fmaf(hu[3], wh[3], a0);
        float a1 = hu[4] * wh[4];
        a1 = fmaf(hu[5], wh[5], a1);
        a1 = fmaf(hu[6], wh[6], a1);
        a1 = fmaf(hu[7], wh[7], a1);
        float a2 = hu[8] * wh[8];
        a2 = fmaf(hu[9], wh[9], a2);
        a2 = fmaf(hu[10], wh[10], a2);
        a2 = fmaf(hu[11], wh[11], a2);
        float a3 = hu[12] * wh[12];
        a3 = fmaf(hu[13], wh[13], a3);
        a3 = fmaf(hu[14], wh[14], a3);
        a3 = fmaf(hu[15], wh[15], a3);
        float gv = (a0 + a1) + (a2 + a3);

        float e = __builtin_amdgcn_exp2f(gv);
        float s = __builtin_amdgcn_rcpf(1.0f + e);
        float act = fmaf(Aa, s, Ba);   // sigmoid, or -2L2E*tanh for gate 2

        int ai = __float_as_int(act);
        float iv = __int_as_float(__builtin_amdgcn_update_dpp(ai, ai, 0x00, 0xF, 0xF, true));
        float fv = __int_as_float(__builtin_amdgcn_update_dpp(ai, ai, 0x55, 0xF, 0xF, true));
        float gs = __int_as_float(__builtin_amdgcn_update_dpp(ai, ai, 0xAA, 0xF, 0xF, true));
        float ov = __int_as_float(__builtin_amdgcn_update_dpp(ai, ai, 0xFF, 0xF, 0xF, true));

        cs = fmaf(fv, cs, iv * gs);    // scaled-domain cell update
        float e2 = __builtin_amdgcn_exp2f(cs);
        float tc = fmaf(2.0f, __builtin_amdgcn_rcpf(1.0f + e2), -1.0f);  // tanh(c)
        float hnew = ov * tc;          // quad-uniform

        hsm[ts * GG + lane] = hnew;    // all lanes store (no exec toggle)

#pragma unroll
        for (int kk = 0; kk < 16; kk++)
          hu[kk] = __uint_as_float(
              __builtin_amdgcn_readlane(__float_as_uint(hnew), 4 * kk));
      }
      gA = gB; gB = gC;
    }
  }
  __syncthreads();

  // ---- Phase 3: output projection ----
  float* outb = out + (size_t)b * TT * CC;
  for (int idx = t; idx < TT * CC; idx += 256) {
    int tt2 = idx / CC;
    int cc = idx - tt2 * CC;
    const float* wr = W_out + cc * HH;
    float accv = b_out[cc];
#pragma unroll
    for (int kk = 0; kk < 16; kk++)
      accv = fmaf(hsm[tt2 * GG + 4 * kk], wr[kk], accv);
    outb[idx] = accv;
  }
}

// ---------------------------------------------------------------------------
extern "C" void kernel_launch(void* const* d_in, const int* in_sizes, int n_in,
                              void* d_out, int out_size, void* d_ws, size_t ws_size,
                              hipStream_t stream) {
  const int*   x     = (const int*)d_in[0];
  const float* emb   = (const float*)d_in[1];
  const float* W_ih  = (const float*)d_in[2];
  const float* W_hh  = (const float*)d_in[3];
  const float* b_ih  = (const float*)d_in[4];
  const float* b_hh  = (const float*)d_in[5];
  const float* W_out = (const float*)d_in[6];
  const float* b_out = (const float*)d_in[7];
  float* out = (float*)d_out;

  lstm_fused_kernel<<<BB, 256, 0, stream>>>(x, emb, W_ih, W_hh, b_ih, b_hh,
                                            W_out, b_out, out);
}